// Round 1
// baseline (392.020 us; speedup 1.0000x reference)
//
#include <hip/hip_runtime.h>
#include <math.h>

// Problem constants
#define BATCH 8
#define LTOT 4096
#define DEMB 1024
#define NH 16
#define DH 64

// ws layout (float offsets) — total ~3.1 MB (old layout needed 17.8 MB; fits)
#define WS_S   0                            // S      [B][1024][16]
#define WS_SV  (WS_S + BATCH*DEMB*NH)       // sv     [B][16]
#define WS_WQ  (WS_SV + BATCH*NH)           // wq_sw  [B][16][1024] (transposed+swizzled)
#define WS_C   (WS_WQ + BATCH*DEMB*NH)      // c      [B][16]
#define WS_V   (WS_C + BATCH*NH)            // V      [B][4096][16]

// Swizzled transposed layout for a [1024][16] matrix staged as [16][1024]:
// logical (h, i) with g=i>>2, lo=i&3 lives at  h*1024 + ((g^h)<<2) + lo.
// float4 read w4[h*256 + (g^h)] returns logical elements i=4g..4g+3, and
// (g+128)^h == (g^h)+128 for g<128, h<16.

// ---------------------------------------------------------------------------
// K1a: v = x@Wv + bv  -> V[b][l][16], plus sv[b][h] = sum_l v.
// 512 blocks (b, 64-row chunk) x 1024 thr; LDS 68KB -> 2 blocks/CU, 32 waves.
// ---------------------------------------------------------------------------
__global__ __launch_bounds__(1024, 8) void k1a_v(
    const float* __restrict__ x, const float* __restrict__ Wv,
    const float* __restrict__ bv, float* __restrict__ V,
    float* __restrict__ sv) {
  __shared__ float wv_sw[DEMB * NH];   // 64 KB
  __shared__ float sv_red[1024];       // 4 KB

  const int b = blockIdx.x >> 6;
  const int l0 = (blockIdx.x & 63) * 64;
  const int t = threadIdx.x;

  // stage Wv[1024][16] -> transposed+swizzled LDS (thread t = row t)
  {
    const float4* wrow = (const float4*)&Wv[(size_t)t * NH];
    const float4 r0 = wrow[0], r1 = wrow[1], r2 = wrow[2], r3 = wrow[3];
    const float vals[16] = {r0.x, r0.y, r0.z, r0.w, r1.x, r1.y, r1.z, r1.w,
                            r2.x, r2.y, r2.z, r2.w, r3.x, r3.y, r3.z, r3.w};
    const int g = t >> 2, lo = t & 3;
    #pragma unroll
    for (int h = 0; h < 16; ++h)
      wv_sw[h * DEMB + (((g ^ h) << 2) + lo)] = vals[h];
  }
  __syncthreads();

  const int h = t & 15;
  const int rp = t >> 4;    // 0..63 -> one row per thread
  const float4* xr = (const float4*)(x + ((size_t)b * LTOT + l0 + rp) * DEMB);
  const float4* wv4 = (const float4*)&wv_sw[h * DEMB];
  float c0 = 0.f, c1 = 0.f;
  #pragma unroll 8
  for (int g = 0; g < 128; ++g) {
    const float4 a0 = xr[g];
    const float4 a1 = xr[g + 128];
    const float4 w0 = wv4[g ^ h];
    const float4 w1 = wv4[(g ^ h) + 128];
    c0 += a0.x * w0.x + a0.y * w0.y + a0.z * w0.z + a0.w * w0.w;
    c1 += a1.x * w1.x + a1.y * w1.y + a1.z * w1.z + a1.w * w1.w;
  }
  const float v = bv[h] + c0 + c1;
  V[((size_t)b * LTOT + l0 + rp) * NH + h] = v;   // coalesced 64B runs
  sv_red[t] = v;
  __syncthreads();
  if (t < 16) {
    float s = 0.f;
    #pragma unroll
    for (int rr = 0; rr < 64; ++rr) s += sv_red[rr * 16 + t];
    atomicAdd(&sv[b * NH + t], s);
  }
}

// ---------------------------------------------------------------------------
// K1s: S[b][i][h] = sum_l x[b][l][i] * V[b][l][h].
// Blocks split by i (16 cols each) -> NO cross-block partials, no Spart.
// 512 blocks (b, ib) x 1024 thr; thread = (hg 4h's, iq 4i's, ls 64-way l-split).
// In-wave shuffle reduce (ls&3) + 16KB LDS reduce across 16 waves.
// x comes from L3 (just streamed by k1a). LDS 16KB -> 2 blocks/CU.
// ---------------------------------------------------------------------------
__global__ __launch_bounds__(1024, 8) void k1s_S(
    const float* __restrict__ x, const float* __restrict__ V,
    float* __restrict__ S) {
  __shared__ float part[16 * 256];   // [wave][i'16][h16], 16 KB

  const int b = blockIdx.x >> 6;
  const int i0 = (blockIdx.x & 63) * 16;
  const int t = threadIdx.x;
  const int hg = t & 3;          // heads hg*4..hg*4+3
  const int iq = (t >> 2) & 3;   // cols i0+iq*4 .. +3
  const int ls = t >> 4;         // 0..63 l-split
  const int w = t >> 6;

  const float4* xr = (const float4*)(x + (size_t)b * LTOT * DEMB);
  const float4* vv = (const float4*)(V + (size_t)b * LTOT * NH);
  const int xoff = (i0 >> 2) + iq;

  float4 aA = {0.f, 0.f, 0.f, 0.f}, aB = aA, aC = aA, aD = aA;
  #pragma unroll 4
  for (int j = 0; j < 64; ++j) {
    const int l = j * 64 + ls;
    const float4 xv = xr[(size_t)l * 256 + xoff];
    const float4 v4 = vv[l * 4 + hg];
    aA.x += xv.x * v4.x; aA.y += xv.x * v4.y; aA.z += xv.x * v4.z; aA.w += xv.x * v4.w;
    aB.x += xv.y * v4.x; aB.y += xv.y * v4.y; aB.z += xv.y * v4.z; aB.w += xv.y * v4.w;
    aC.x += xv.z * v4.x; aC.y += xv.z * v4.y; aC.z += xv.z * v4.z; aC.w += xv.z * v4.w;
    aD.x += xv.w * v4.x; aD.y += xv.w * v4.y; aD.z += xv.w * v4.z; aD.w += xv.w * v4.w;
  }

  // butterfly reduce over the two ls bits inside the wave (t bits 4,5)
  #define SH_ADD(v, m)                                          \
    v.x += __shfl_xor(v.x, m); v.y += __shfl_xor(v.y, m);       \
    v.z += __shfl_xor(v.z, m); v.w += __shfl_xor(v.w, m);
  SH_ADD(aA, 16) SH_ADD(aB, 16) SH_ADD(aC, 16) SH_ADD(aD, 16)
  SH_ADD(aA, 32) SH_ADD(aB, 32) SH_ADD(aC, 32) SH_ADD(aD, 32)
  #undef SH_ADD

  if ((t & 48) == 0) {           // one writer lane per (hg,iq) per wave
    float* p0 = &part[w * 256 + (iq * 4) * 16 + hg * 4];
    *(float4*)&p0[0]  = aA;
    *(float4*)&p0[16] = aB;
    *(float4*)&p0[32] = aC;
    *(float4*)&p0[48] = aD;
  }
  __syncthreads();
  if (t < 256) {
    const int ii = t >> 4, h2 = t & 15;
    float s = 0.f;
    #pragma unroll
    for (int ww = 0; ww < 16; ++ww) s += part[ww * 256 + ii * 16 + h2];
    S[((size_t)b << 14) + (size_t)(i0 + ii) * NH + h2] = s;  // coalesced
  }
}

// ---------------------------------------------------------------------------
// K2: ktv + wq_eff (written transposed+swizzled) + c. grid B*NH, 1024 thr.
// Wk read vectorized (float4 over d), 64-way i-split reduce.
// ---------------------------------------------------------------------------
__global__ __launch_bounds__(1024) void k2_ktv_wq(
    const float* __restrict__ Wq, const float* __restrict__ bq,
    const float* __restrict__ Wk, const float* __restrict__ bk,
    const float* __restrict__ S, const float* __restrict__ sv,
    float* __restrict__ wq_sw, float* __restrict__ cvec) {
  __shared__ float kpart[64][64];   // [iseg][d] 16 KB
  __shared__ float ktv[DH];
  const int b = blockIdx.x >> 4;
  const int h = blockIdx.x & 15;
  const int t = threadIdx.x;
  const float* Sb = S + ((size_t)b << 14);

  {
    const int d4 = t & 15;       // d = d4*4..+3
    const int iseg = t >> 4;     // 64 segs x 16 i
    const float* wkbase = Wk + h * DH + d4 * 4;
    float4 kp = {0.f, 0.f, 0.f, 0.f};
    #pragma unroll 4
    for (int i = iseg * 16; i < iseg * 16 + 16; ++i) {
      const float4 w4 = *(const float4*)&wkbase[(size_t)i * DEMB];
      const float sS = Sb[i * NH + h];
      kp.x += w4.x * sS; kp.y += w4.y * sS; kp.z += w4.z * sS; kp.w += w4.w * sS;
    }
    *(float4*)&kpart[iseg][d4 * 4] = kp;
  }
  __syncthreads();
  if (t < 64) {
    float s = 0.f;
    #pragma unroll
    for (int seg = 0; seg < 64; ++seg) s += kpart[seg][t];
    s += bk[h * DH + t] * sv[b * NH + h];
    ktv[t] = s;
  }
  __syncthreads();

  {
    const int i = t;
    const float* wrow = &Wq[(size_t)i * DEMB + h * DH];
    float s0 = 0.f, s1 = 0.f;
    #pragma unroll
    for (int dd = 0; dd < DH; dd += 8) {
      const float4 w4 = *(const float4*)&wrow[dd];
      const float4 w5 = *(const float4*)&wrow[dd + 4];
      s0 += w4.x * ktv[dd] + w4.y * ktv[dd + 1] + w4.z * ktv[dd + 2] + w4.w * ktv[dd + 3];
      s1 += w5.x * ktv[dd + 4] + w5.y * ktv[dd + 5] + w5.z * ktv[dd + 6] + w5.w * ktv[dd + 7];
    }
    wq_sw[(size_t)b * DEMB * NH + h * DEMB + ((((i >> 2) ^ h) << 2) + (i & 3))] = s0 + s1;
  }
  if (t == 0) {
    float s = 0.f;
    for (int dd = 0; dd < DH; ++dd) s += bq[h * DH + dd] * ktv[dd];
    cvec[b * NH + h] = s;
  }
}

// ---------------------------------------------------------------------------
// K3: z = (x . wq_eff + c)/8 -> sigmoid -> mask.
// 512 blocks (b, 64-row chunk) x 1024 thr, 1 row/thread, 2 blocks/CU.
// ---------------------------------------------------------------------------
__global__ __launch_bounds__(1024, 8) void k3_z_sigmoid(
    const float* __restrict__ x, const int* __restrict__ mask,
    const float* __restrict__ wq_sw_g, const float* __restrict__ cvec,
    float* __restrict__ out) {
  __shared__ float wq_sw[DEMB * NH];   // 64 KB (already swizzled in global)
  __shared__ float c_lds[NH];

  const int b = blockIdx.x >> 6;
  const int l0 = (blockIdx.x & 63) * 64;
  const int t = threadIdx.x;

  const float4* src = (const float4*)(wq_sw_g + (size_t)b * DEMB * NH);
  float4* dst = (float4*)wq_sw;
  #pragma unroll
  for (int j = t; j < DEMB * NH / 4; j += 1024) dst[j] = src[j];
  if (t < 16) c_lds[t] = cvec[b * NH + t];
  __syncthreads();

  const int h = t & 15;
  const int rp = t >> 4;     // 0..63
  const int l = l0 + rp;
  const float4* xr = (const float4*)(x + ((size_t)b * LTOT + l) * DEMB);
  const float4* wq4 = (const float4*)&wq_sw[h * DEMB];
  float c0 = 0.f, c1 = 0.f;
  #pragma unroll 8
  for (int g = 0; g < 128; ++g) {
    const float4 a0 = xr[g];
    const float4 a1 = xr[g + 128];
    const float4 w0 = wq4[g ^ h];
    const float4 w1 = wq4[(g ^ h) + 128];
    c0 += a0.x * w0.x + a0.y * w0.y + a0.z * w0.z + a0.w * w0.w;
    c1 += a1.x * w1.x + a1.y * w1.y + a1.z * w1.z + a1.w * w1.w;
  }
  const float z = (c_lds[h] + c0 + c1) * 0.125f;
  float p = 1.f / (1.f + __expf(-z));
  if (mask[b * LTOT + l] == 0) p = 0.f;
  out[((size_t)(b * NH + h)) * LTOT + l] = p;
}

extern "C" void kernel_launch(void* const* d_in, const int* in_sizes, int n_in,
                              void* d_out, int out_size, void* d_ws, size_t ws_size,
                              hipStream_t stream) {
  const float* x  = (const float*)d_in[0];
  const int* mask = (const int*)d_in[1];
  const float* Wq = (const float*)d_in[2];
  const float* bq = (const float*)d_in[3];
  const float* Wk = (const float*)d_in[4];
  const float* bk = (const float*)d_in[5];
  const float* Wv = (const float*)d_in[6];
  const float* bv = (const float*)d_in[7];
  float* out = (float*)d_out;
  float* ws = (float*)d_ws;

  float* S     = ws + WS_S;
  float* sv    = ws + WS_SV;
  float* wq_sw = ws + WS_WQ;
  float* cvec  = ws + WS_C;
  float* V     = ws + WS_V;

  hipMemsetAsync(sv, 0, BATCH * NH * sizeof(float), stream);

  k1a_v<<<dim3(BATCH * 64), dim3(1024), 0, stream>>>(x, Wv, bv, V, sv);
  k1s_S<<<dim3(BATCH * 64), dim3(1024), 0, stream>>>(x, V, S);
  k2_ktv_wq<<<dim3(BATCH * NH), dim3(1024), 0, stream>>>(Wq, bq, Wk, bk, S, sv, wq_sw, cvec);
  k3_z_sigmoid<<<dim3(BATCH * 64), dim3(1024), 0, stream>>>(x, mask, wq_sw, cvec, out);
}

// Round 2
// 323.448 us; speedup vs baseline: 1.2120x; 1.2120x over previous
//
#include <hip/hip_runtime.h>
#include <math.h>

// Problem constants
#define BATCH 8
#define LTOT 4096
#define DEMB 1024
#define NH 16
#define DH 64

// ws layout (float offsets) — ~3.1 MB total
#define WS_S   0                            // S      [B][1024][16]
#define WS_SV  (WS_S + BATCH*DEMB*NH)       // sv     [B][16]
#define WS_WQ  (WS_SV + BATCH*NH)           // wq_nat [B][1024][16] (natural layout)
#define WS_C   (WS_WQ + BATCH*DEMB*NH)      // c      [B][16]
#define WS_V   (WS_C + BATCH*NH)            // V      [B][4096][16]

#define FMA4(A, s, W) { (A).x += (s)*(W).x; (A).y += (s)*(W).y; (A).z += (s)*(W).z; (A).w += (s)*(W).w; }

// ---------------------------------------------------------------------------
// xw_core<MODE>: y[l][h] = x[l][:] . W[:][h]  for 64 rows per block.
//   MODE 0 (k1a): W=Wv, epilogue v=sum+bv -> V[b][l][16] + sv reduction.
//   MODE 1 (k3):  W=wq_nat[b], epilogue z=(sum+c)/8 -> sigmoid -> mask -> out.
// 512 thr, grid B*64. Slices of 64 i: x tile [64][64] f32 XOR-swizzled in LDS,
// reg-prefetch global->LDS. Thread = (is=t>>5: one i-quad/slice, rq=t&31: 2 rows),
// acc = 2 rows x 16 heads. Per slice/thread: 2+16 LDS reads, 128 FMAs.
// W-quad reads are wave-broadcast (is uniform per half-wave).
// Final reduce over 16 is-partials via LDS. LDS 66KB -> 2 blocks/CU (16 waves).
// ---------------------------------------------------------------------------
template <int MODE>
__global__ __launch_bounds__(512, 4) void xw_core(
    const float* __restrict__ x, const float* __restrict__ Wg,
    const float* __restrict__ aux,          // MODE0: bv[16]; MODE1: cvec[B][16]
    const int* __restrict__ mask,           // MODE1 only
    float* __restrict__ outp,               // MODE0: V; MODE1: out
    float* __restrict__ sv) {               // MODE0 only
  __shared__ float lds[16384];              // compute: xs[0..4096) + ws[4096..5120); epi: part[16][64][16]
  __shared__ float aux_l[512];              // MODE0: svred[32][16]; MODE1: c_lds[16]

  const int bid = blockIdx.x;
  const int b = bid >> 6;
  const int l0 = (bid & 63) * 64;
  const int t = threadIdx.x;
  const int is = t >> 5;     // 0..15: i-quad within slice
  const int rq = t & 31;     // rows 2rq, 2rq+1

  const float* W = (MODE == 0) ? Wg : (Wg + ((size_t)b << 14));
  const float4* xg = (const float4*)(x + ((size_t)(b * LTOT + l0)) * DEMB);

  // staging indices (thread t stages x float4s #t and #t+512 of the 64x16 tile, 2 w floats)
  const int sr0 = t >> 4, sc = t & 15;         // row 0..31, col-quad
  const int sr1 = sr0 + 32;
  const int swz = (t >> 5) & 7;                // (r>>1)&7, same for sr0/sr1 pair rows
  const int wi = t >> 3, wh = t & 7;           // w: row-in-slice, h-pair

  float4* xs4 = (float4*)lds;                  // swizzled [64][16] float4
  float4* ws4 = (float4*)(lds + 4096);         // natural  [64][4]  float4

  // prefetch slice 0
  float4 gx0 = xg[sr0 * 256 + sc];
  float4 gx1 = xg[sr1 * 256 + sc];
  float2 gw = *(const float2*)&W[(size_t)wi * NH + wh * 2];

  float4 acc0[4] = {{0,0,0,0},{0,0,0,0},{0,0,0,0},{0,0,0,0}};
  float4 acc1[4] = {{0,0,0,0},{0,0,0,0},{0,0,0,0},{0,0,0,0}};

  const int c4p = is ^ (rq & 7);               // swizzled read col for this thread's quad

  for (int s = 0; s < 16; ++s) {
    __syncthreads();                           // prev compute done; safe to overwrite tiles
    xs4[sr0 * 16 + (sc ^ swz)] = gx0;
    xs4[sr1 * 16 + (sc ^ swz)] = gx1;
    *(float2*)&lds[4096 + wi * 16 + wh * 2] = gw;
    __syncthreads();                           // tiles visible
    if (s < 15) {                              // prefetch next slice (hidden under compute)
      gx0 = xg[sr0 * 256 + (s + 1) * 16 + sc];
      gx1 = xg[sr1 * 256 + (s + 1) * 16 + sc];
      gw = *(const float2*)&W[(size_t)((s + 1) * 64 + wi) * NH + wh * 2];
    }
    const float4 xr0 = xs4[(2 * rq) * 16 + c4p];       // x[2rq][s*64+is*4 .. +3]
    const float4 xr1 = xs4[(2 * rq + 1) * 16 + c4p];
    const int ilb = (is << 2) << 2;                    // (is*4)*4: float4 idx base in ws4
    #define STEP(II, COMP)                                            \
    {                                                                 \
      const float4 w0 = ws4[ilb + (II)*4 + 0];                        \
      const float4 w1 = ws4[ilb + (II)*4 + 1];                        \
      const float4 w2 = ws4[ilb + (II)*4 + 2];                        \
      const float4 w3 = ws4[ilb + (II)*4 + 3];                        \
      const float xa = xr0.COMP, xb = xr1.COMP;                       \
      FMA4(acc0[0], xa, w0) FMA4(acc0[1], xa, w1)                     \
      FMA4(acc0[2], xa, w2) FMA4(acc0[3], xa, w3)                     \
      FMA4(acc1[0], xb, w0) FMA4(acc1[1], xb, w1)                     \
      FMA4(acc1[2], xb, w2) FMA4(acc1[3], xb, w3)                     \
    }
    STEP(0, x) STEP(1, y) STEP(2, z) STEP(3, w)
    #undef STEP
  }

  // ---- epilogue: reduce 16 is-partials. part[is][r][h], word = is*1024 + r*16 + h
  __syncthreads();
  {
    float4* p4 = (float4*)lds;
    const int base0 = is * 256 + (2 * rq) * 4;
    const int base1 = base0 + 4;
    p4[base0 + 0] = acc0[0]; p4[base0 + 1] = acc0[1];
    p4[base0 + 2] = acc0[2]; p4[base0 + 3] = acc0[3];
    p4[base1 + 0] = acc1[0]; p4[base1 + 1] = acc1[1];
    p4[base1 + 2] = acc1[2]; p4[base1 + 3] = acc1[3];
  }
  if (MODE == 1 && t < NH) aux_l[t] = aux[b * NH + t];
  __syncthreads();

  if (MODE == 0) {
    // thread = (h = t&15, rp = t>>4): rows 2rp,2rp+1 -> contiguous 64B V writes
    const int h = t & 15, rp = t >> 4;
    float s0 = 0.f, s1 = 0.f;
    #pragma unroll
    for (int k = 0; k < 16; ++k) {
      s0 += lds[k * 1024 + (2 * rp) * 16 + h];
      s1 += lds[k * 1024 + (2 * rp + 1) * 16 + h];
    }
    const float bvh = aux[h];
    const float v0 = s0 + bvh, v1 = s1 + bvh;
    outp[((size_t)(b * LTOT + l0 + 2 * rp)) * NH + h] = v0;
    outp[((size_t)(b * LTOT + l0 + 2 * rp + 1)) * NH + h] = v1;
    aux_l[rp * 16 + h] = v0 + v1;
    __syncthreads();
    if (t < NH) {
      float ss = 0.f;
      #pragma unroll
      for (int rr = 0; rr < 32; ++rr) ss += aux_l[rr * 16 + t];
      atomicAdd(&sv[b * NH + t], ss);
    }
  } else {
    // thread = (r = t&63, hp = t>>6): 256B-contiguous out writes per h-plane
    const int r = t & 63, hp = t >> 6;
    float m0 = 0.f, m1 = 0.f;
    #pragma unroll
    for (int k = 0; k < 16; ++k) {
      const float2 u = *(const float2*)&lds[k * 1024 + r * 16 + 2 * hp];
      m0 += u.x; m1 += u.y;
    }
    const float z0 = (m0 + aux_l[2 * hp]) * 0.125f;
    const float z1 = (m1 + aux_l[2 * hp + 1]) * 0.125f;
    float p0 = 1.f / (1.f + __expf(-z0));
    float p1 = 1.f / (1.f + __expf(-z1));
    if (mask[b * LTOT + l0 + r] == 0) { p0 = 0.f; p1 = 0.f; }
    outp[((size_t)(b * NH + 2 * hp)) * LTOT + l0 + r] = p0;
    outp[((size_t)(b * NH + 2 * hp + 1)) * LTOT + l0 + r] = p1;
  }
}

// ---------------------------------------------------------------------------
// K1s: S[b][i][h] += sum_l x[b][l][i] * V[b][l][h].
// Grid 512 = (b, ib: 64-i window, lh: 1024-l range). 512 thr.
// Thread = (iq=t&7: x-col float4s {iq,iq+8}, hg=(t>>3)&3: 4 heads, ls=t>>5: l mod 16).
// Per iter: 2 x float4 (2x128B contiguous/wave) + 1 v float4 (64B runs) + 32 FMAs.
// LDS reduce over 16 ls, then 2 atomicAdds/thread into S (4-way contention).
// ---------------------------------------------------------------------------
__global__ __launch_bounds__(512, 4) void k1s_S(
    const float* __restrict__ x, const float* __restrict__ V,
    float* __restrict__ S) {
  __shared__ float lds[16384];   // part[16 ls][64 i][16 h]

  const int bid = blockIdx.x;
  const int b = bid >> 6;
  const int ib = (bid >> 2) & 15;
  const int lh = bid & 3;
  const int t = threadIdx.x;
  const int iq = t & 7;
  const int hg = (t >> 3) & 3;
  const int ls = t >> 5;

  const float4* xg = (const float4*)(x + ((size_t)(b * LTOT + lh * 1024)) * DEMB);
  const float4* vg = (const float4*)(V + ((size_t)(b * LTOT + lh * 1024)) * NH);
  const int xc0 = ib * 16 + iq, xc1 = xc0 + 8;

  float4 a0[4] = {{0,0,0,0},{0,0,0,0},{0,0,0,0},{0,0,0,0}};
  float4 a1[4] = {{0,0,0,0},{0,0,0,0},{0,0,0,0},{0,0,0,0}};

  #pragma unroll 4
  for (int it = 0; it < 64; ++it) {
    const int l = it * 16 + ls;
    const float4 xq0 = xg[(size_t)l * 256 + xc0];
    const float4 xq1 = xg[(size_t)l * 256 + xc1];
    const float4 vv = vg[l * 4 + hg];
    FMA4(a0[0], xq0.x, vv) FMA4(a0[1], xq0.y, vv)
    FMA4(a0[2], xq0.z, vv) FMA4(a0[3], xq0.w, vv)
    FMA4(a1[0], xq1.x, vv) FMA4(a1[1], xq1.y, vv)
    FMA4(a1[2], xq1.z, vv) FMA4(a1[3], xq1.w, vv)
  }

  // part[ls][i_local][h]: float4 idx = ls*256 + i_local*4 + hg
  {
    float4* p4 = (float4*)lds;
    #pragma unroll
    for (int ii = 0; ii < 4; ++ii) {
      p4[ls * 256 + (iq * 4 + ii) * 4 + hg] = a0[ii];
      p4[ls * 256 + ((iq + 8) * 4 + ii) * 4 + hg] = a1[ii];
    }
  }
  __syncthreads();
  {
    const int il = t & 63, hp = t >> 6;
    float m0 = 0.f, m1 = 0.f;
    #pragma unroll
    for (int k = 0; k < 16; ++k) {
      const float2 u = *(const float2*)&lds[k * 1024 + il * 16 + 2 * hp];
      m0 += u.x; m1 += u.y;
    }
    float* dst = &S[((size_t)b << 14) + (size_t)(ib * 64 + il) * NH + 2 * hp];
    atomicAdd(dst, m0);
    atomicAdd(dst + 1, m1);
  }
}

// ---------------------------------------------------------------------------
// K2: ktv + wq_eff (natural [1024][16] layout) + c. grid B*NH, 1024 thr.
// ---------------------------------------------------------------------------
__global__ __launch_bounds__(1024) void k2_ktv_wq(
    const float* __restrict__ Wq, const float* __restrict__ bq,
    const float* __restrict__ Wk, const float* __restrict__ bk,
    const float* __restrict__ S, const float* __restrict__ sv,
    float* __restrict__ wq_nat, float* __restrict__ cvec) {
  __shared__ float kpart[64][64];   // [iseg][d] 16 KB
  __shared__ float ktv[DH];
  const int b = blockIdx.x >> 4;
  const int h = blockIdx.x & 15;
  const int t = threadIdx.x;
  const float* Sb = S + ((size_t)b << 14);

  {
    const int d4 = t & 15;       // d = d4*4..+3
    const int iseg = t >> 4;     // 64 segs x 16 i
    const float* wkbase = Wk + h * DH + d4 * 4;
    float4 kp = {0.f, 0.f, 0.f, 0.f};
    #pragma unroll 4
    for (int i = iseg * 16; i < iseg * 16 + 16; ++i) {
      const float4 w4 = *(const float4*)&wkbase[(size_t)i * DEMB];
      const float sS = Sb[i * NH + h];
      kp.x += w4.x * sS; kp.y += w4.y * sS; kp.z += w4.z * sS; kp.w += w4.w * sS;
    }
    *(float4*)&kpart[iseg][d4 * 4] = kp;
  }
  __syncthreads();
  if (t < 64) {
    float s = 0.f;
    #pragma unroll
    for (int seg = 0; seg < 64; ++seg) s += kpart[seg][t];
    s += bk[h * DH + t] * sv[b * NH + h];
    ktv[t] = s;
  }
  __syncthreads();

  {
    const int i = t;
    const float* wrow = &Wq[(size_t)i * DEMB + h * DH];
    float s0 = 0.f, s1 = 0.f;
    #pragma unroll
    for (int dd = 0; dd < DH; dd += 8) {
      const float4 w4 = *(const float4*)&wrow[dd];
      const float4 w5 = *(const float4*)&wrow[dd + 4];
      s0 += w4.x * ktv[dd] + w4.y * ktv[dd + 1] + w4.z * ktv[dd + 2] + w4.w * ktv[dd + 3];
      s1 += w5.x * ktv[dd + 4] + w5.y * ktv[dd + 5] + w5.z * ktv[dd + 6] + w5.w * ktv[dd + 7];
    }
    wq_nat[((size_t)b << 14) + (size_t)i * NH + h] = s0 + s1;
  }
  if (t == 0) {
    float s = 0.f;
    for (int dd = 0; dd < DH; ++dd) s += bq[h * DH + dd] * ktv[dd];
    cvec[b * NH + h] = s;
  }
}

extern "C" void kernel_launch(void* const* d_in, const int* in_sizes, int n_in,
                              void* d_out, int out_size, void* d_ws, size_t ws_size,
                              hipStream_t stream) {
  const float* x  = (const float*)d_in[0];
  const int* mask = (const int*)d_in[1];
  const float* Wq = (const float*)d_in[2];
  const float* bq = (const float*)d_in[3];
  const float* Wk = (const float*)d_in[4];
  const float* bk = (const float*)d_in[5];
  const float* Wv = (const float*)d_in[6];
  const float* bv = (const float*)d_in[7];
  float* out = (float*)d_out;
  float* ws = (float*)d_ws;

  float* S      = ws + WS_S;
  float* sv     = ws + WS_SV;
  float* wq_nat = ws + WS_WQ;
  float* cvec   = ws + WS_C;
  float* V      = ws + WS_V;

  hipMemsetAsync(sv, 0, BATCH * NH * sizeof(float), stream);
  hipMemsetAsync(S, 0, (size_t)BATCH * DEMB * NH * sizeof(float), stream);

  xw_core<0><<<dim3(BATCH * 64), dim3(512), 0, stream>>>(x, Wv, bv, nullptr, V, sv);
  k1s_S<<<dim3(BATCH * 64), dim3(512), 0, stream>>>(x, V, S);
  k2_ktv_wq<<<dim3(BATCH * NH), dim3(1024), 0, stream>>>(Wq, bq, Wk, bk, S, sv, wq_nat, cvec);
  xw_core<1><<<dim3(BATCH * 64), dim3(512), 0, stream>>>(x, wq_nat, cvec, mask, out, nullptr);
}